// Round 13
// baseline (12.090 us; speedup 1.0000x reference)
//
#include <hip/hip_runtime.h>
#include <hip/hip_bf16.h>
#include <math.h>

#define NB    512
#define DXN   100
#define MROW  128
#define TC    130
#define G     16     // rows per block
#define BT    512
#define KP    128    // padded K
#define AP    136    // LDS row stride (shorts)
#define T0f   (-5.0f)
#define Hf    (10.0f / 99.0f)
#define LOG2E 1.4426950408889634f
#define WLO   42     // K-active t-window [42, 74)

typedef __attribute__((ext_vector_type(8))) short  short8;
typedef __attribute__((ext_vector_type(4))) float  f32x4;

__device__ __forceinline__ float Tval(int t) { return T0f + Hf * (float)t; }

__device__ __forceinline__ unsigned short f2bf(float x) {
    __hip_bfloat16 b = __float2bfloat16(x);
    unsigned short u; __builtin_memcpy(&u, &b, 2); return u;
}
__device__ __forceinline__ float bf2f(unsigned short h) {
    return __uint_as_float(((unsigned)h) << 16);
}
__device__ __forceinline__ unsigned pk2bf(float lo, float hi) {
    __hip_bfloat162 b2 = __float22bfloat162_rn(float2{lo, hi});
    unsigned u; __builtin_memcpy(&u, &b2, 4); return u;
}

// R12 structure (11.91 us) with phases 2b+3 merged and B2/s_f deleted:
// waves 0-1 compute f via MFMA and write window-t dw directly from the
// accumulator; waves 2-7 concurrently fill the 68 non-window + 28 pad
// t-columns (f==0 there). 2 barriers total. Per-row scalars derived
// per-consumer from raw th0/th1 (rcp), so no scalar-publish phase.
__global__ __launch_bounds__(BT) void fused_kernel(
    const float* __restrict__ theta,
    const float* __restrict__ mu,
    const float* __restrict__ sigma,
    float* __restrict__ out, int Bn)
{
    __shared__ __align__(16) unsigned short sB[NB * AP];     // 139264 B
    __shared__ __align__(16) unsigned short sAlH[G * AP];    // alpha hi
    __shared__ __align__(16) unsigned short sAlL[G * AP];    // alpha lo
    __shared__ __align__(16) unsigned short sAh[G * AP];     // dw hi
    __shared__ __align__(16) unsigned short sAl[G * AP];     // dw lo
    __shared__ __align__(16) float s_th0[G];                 // raw theta0
    __shared__ __align__(16) float s_th1[G];                 // raw theta1

    const int tid  = threadIdx.x;
    const int b0   = blockIdx.x * G;
    const int lane = tid & 63;
    const int wv   = tid >> 6;
    const int lrow = lane & 15;
    const int kg   = (lane >> 4) * 8;

    // ---- issue all global loads up front ----
    const float mun = mu[tid];
    const float sgn = sigma[tid];
    float tv[5];
    #pragma unroll
    for (int k = 0; k < 5; ++k) {
        int i = tid + k * BT;
        int r = i / TC, c = i - r * TC;
        int br = b0 + r; if (br >= Bn) br = Bn - 1;
        tv[k] = (i < G * TC) ? theta[br * TC + c] : 0.0f;
    }

    // ---- Phase 0: B = phi bf16 [col][k]; multiplicative recurrence, restart /16 ----
    {
        const float inv_s = 1.0f / sgn;
        const float dlt = Hf * inv_s;
        const float Lh  = 0.5f * LOG2E;
        const float cc  = -2.0f * Lh * dlt * dlt;
        const float srt = __builtin_amdgcn_exp2f(cc);        // ratio-of-ratios
        const float S   = __log2f(0.3989422804014327f * inv_s);
        unsigned short* myB = &sB[tid * AP];
        #pragma unroll
        for (int k0 = 0; k0 < 96; k0 += 16) {
            float u  = (mun - Tval(k0)) * inv_s;
            float p  = __builtin_amdgcn_exp2f(S - Lh * u * u);
            float r  = __builtin_amdgcn_exp2f(Lh * dlt * (2.0f * u - dlt));
            unsigned w[8];
            #pragma unroll
            for (int j = 0; j < 8; ++j) {
                float p0 = p; p *= r; r *= srt;
                float p1 = p; p *= r; r *= srt;
                w[j] = pk2bf(p0, p1);
            }
            *(uint4*)&myB[k0]     = make_uint4(w[0], w[1], w[2], w[3]);
            *(uint4*)&myB[k0 + 8] = make_uint4(w[4], w[5], w[6], w[7]);
        }
        {   // k = 96..99 real, 100..127 zero pad
            float u  = (mun - Tval(96)) * inv_s;
            float p  = __builtin_amdgcn_exp2f(S - Lh * u * u);
            float r  = __builtin_amdgcn_exp2f(Lh * dlt * (2.0f * u - dlt));
            float p0 = p; p *= r; r *= srt;
            float p1 = p; p *= r; r *= srt;
            unsigned w0 = pk2bf(p0, p1);
            p0 = p; p *= r;
            p1 = p;
            unsigned w1 = pk2bf(p0, p1);
            *(uint4*)&myB[96]  = make_uint4(w0, w1, 0u, 0u);
            *(uint4*)&myB[104] = make_uint4(0u, 0u, 0u, 0u);
            *(uint4*)&myB[112] = make_uint4(0u, 0u, 0u, 0u);
            *(uint4*)&myB[120] = make_uint4(0u, 0u, 0u, 0u);
        }
    }

    // ---- Phase 1: theta -> alpha bf16 hi/lo + raw th0/th1 ----
    #pragma unroll
    for (int k = 0; k < 5; ++k) {
        int i = tid + k * BT;
        if (i < G * TC) {
            int r = i / TC, c = i - r * TC;
            float v = tv[k];
            if (c >= 2) {
                unsigned short h = f2bf(v);
                sAlH[r * AP + (c - 2)] = h;
                sAlL[r * AP + (c - 2)] = f2bf(v - bf2f(h));
            } else if (c == 0) s_th0[r] = v;
            else               s_th1[r] = v;
        }
    }
    __syncthreads();   // B1

    // ---- Phase 2 (merged): waves 0-1 f-MFMA -> window dw in-register;
    //      waves 2-7 fill non-window + pad dw concurrently ----
    if (wv < 2) {
        const int t   = WLO + wv * 16 + lrow;    // this lane's t (42..73)
        const float T = Tval(t);
        const float C2 = 50.0f * LOG2E;
        const float dj = 1.0f / 127.0f;
        const float sK = __builtin_amdgcn_exp2f(-2.0f * C2 * dj * dj);
        f32x4 fa = {0.0f, 0.0f, 0.0f, 0.0f};
        #pragma unroll
        for (int ks = 0; ks < 4; ++ks) {
            short8 ah = *(const short8*)&sAlH[lrow * AP + ks * 32 + kg];
            short8 al = *(const short8*)&sAlL[lrow * AP + ks * 32 + kg];
            float d0 = (float)(ks * 32 + kg) * dj - T;
            float p  = __builtin_amdgcn_exp2f(-C2 * d0 * d0);
            float r  = __builtin_amdgcn_exp2f(-C2 * dj * (2.0f * d0 + dj));
            short8 kh, kl;
            #pragma unroll
            for (int jj = 0; jj < 8; ++jj) {
                float kv = p; p *= r; r *= sK;
                unsigned short h = f2bf(kv);
                kh[jj] = (short)h;
                kl[jj] = (short)f2bf(kv - bf2f(h));
            }
            fa = __builtin_amdgcn_mfma_f32_16x16x32_bf16(ah, kh, fa, 0, 0, 0);
            fa = __builtin_amdgcn_mfma_f32_16x16x32_bf16(al, kh, fa, 0, 0, 0);
            fa = __builtin_amdgcn_mfma_f32_16x16x32_bf16(ah, kl, fa, 0, 0, 0);
        }
        // dw for this lane's 4 rows at its window t, straight from the accumulator
        #pragma unroll
        for (int j = 0; j < 4; ++j) {
            const int row = (lane >> 4) * 4 + j;
            float th1 = s_th1[row];                          // <= -0.5
            float muc = s_th0[row] * (-0.5f * __builtin_amdgcn_rcpf(th1));
            float dm  = muc - T;
            float e   = fmaxf(1.0f + fa[j] + th1 * dm * dm, 1e-8f);  // -nth = th1
            float dw  = e * Hf;                              // t in [42,74): never edge
            unsigned short h = f2bf(dw);
            sAh[row * AP + t] = h;
            sAl[row * AP + t] = f2bf(dw - bf2f(h));
        }
    } else {
        // 16 rows x 96 cols (68 non-window + 28 pad) = 1536 tasks over 384 lanes
        #pragma unroll
        for (int rd = 0; rd < 4; ++rd) {
            int task = rd * 384 + (wv - 2) * 64 + lane;
            int row  = task / 96;
            int q    = task - row * 96;
            if (q < 68) {
                int t = (q < WLO) ? q : q + 32;              // [0,42) or [74,100)
                float th1 = s_th1[row];
                float muc = s_th0[row] * (-0.5f * __builtin_amdgcn_rcpf(th1));
                float dm  = muc - Tval(t);
                float e   = fmaxf(1.0f + th1 * dm * dm, 1e-8f);   // f == 0 here
                float w   = (t == 0 || t == DXN - 1) ? Hf * 0.5f : Hf;
                float dw  = e * w;
                unsigned short h = f2bf(dw);
                sAh[row * AP + t] = h;
                sAl[row * AP + t] = f2bf(dw - bf2f(h));
            } else {
                int t = q + 32;                              // [100,128) zero pad
                sAh[row * AP + t] = 0;
                sAl[row * AP + t] = 0;
            }
        }
    }
    __syncthreads();   // B2 (last barrier)

    // ---- Phase 4: A-frags, per-wave Z via ones-MFMA, GEMM vs sB, epilogue ----
    short8 Ah[4], Al[4];
    #pragma unroll
    for (int ks = 0; ks < 4; ++ks) {
        Ah[ks] = *(const short8*)&sAh[lrow * AP + ks * 32 + kg];
        Al[ks] = *(const short8*)&sAl[lrow * AP + ks * 32 + kg];
    }

    short8 ones;
    #pragma unroll
    for (int jj = 0; jj < 8; ++jj) ones[jj] = (short)0x3F80;   // bf16 1.0
    f32x4 az = {0.0f, 0.0f, 0.0f, 0.0f};
    #pragma unroll
    for (int ks = 0; ks < 4; ++ks) {
        az = __builtin_amdgcn_mfma_f32_16x16x32_bf16(Ah[ks], ones, az, 0, 0, 0);
        az = __builtin_amdgcn_mfma_f32_16x16x32_bf16(Al[ks], ones, az, 0, 0, 0);
    }
    float iz[4];
    #pragma unroll
    for (int j = 0; j < 4; ++j) iz[j] = __builtin_amdgcn_rcpf(az[j]);

    #pragma unroll
    for (int ct = 0; ct < 4; ++ct) {
        const int n = wv * 64 + ct * 16 + lrow;
        f32x4 a = {0.0f, 0.0f, 0.0f, 0.0f};
        #pragma unroll
        for (int ks = 0; ks < 4; ++ks) {
            short8 b = *(const short8*)&sB[n * AP + ks * 32 + kg];
            a = __builtin_amdgcn_mfma_f32_16x16x32_bf16(Ah[ks], b, a, 0, 0, 0);
            a = __builtin_amdgcn_mfma_f32_16x16x32_bf16(Al[ks], b, a, 0, 0, 0);
        }
        #pragma unroll
        for (int j = 0; j < 4; ++j) {
            int row = b0 + (lane >> 4) * 4 + j;
            if (row < Bn) out[row * NB + n] = a[j] * iz[j];
        }
    }
}

extern "C" void kernel_launch(void* const* d_in, const int* in_sizes, int n_in,
                              void* d_out, int out_size, void* d_ws, size_t ws_size,
                              hipStream_t stream) {
    const float* theta = (const float*)d_in[0];
    const float* mu    = (const float*)d_in[1];
    const float* sigma = (const float*)d_in[2];
    float* outp = (float*)d_out;

    int Bn = in_sizes[0] / TC;                  // 4096
    int grid = (Bn + G - 1) / G;                // 256 blocks -> 1 per CU
    fused_kernel<<<grid, BT, 0, stream>>>(theta, mu, sigma, outp, Bn);
}

// Round 14
// 11.869 us; speedup vs baseline: 1.0186x; 1.0186x over previous
//
#include <hip/hip_runtime.h>
#include <hip/hip_bf16.h>
#include <math.h>

#define NB    512
#define DXN   100
#define MROW  128
#define TC    130
#define G     16     // rows per block
#define BT    512
#define KP    128    // padded K
#define AP    136    // LDS row stride (shorts)
#define T0f   (-5.0f)
#define Hf    (10.0f / 99.0f)
#define LOG2E 1.4426950408889634f
#define WLO   42     // K-active t-window start; s_f covers t in [42, 74)

typedef __attribute__((ext_vector_type(8))) short  short8;
typedef __attribute__((ext_vector_type(4))) float  f32x4;

__device__ __forceinline__ float Tval(int t) { return T0f + Hf * (float)t; }

__device__ __forceinline__ unsigned short f2bf(float x) {
    __hip_bfloat16 b = __float2bfloat16(x);
    unsigned short u; __builtin_memcpy(&u, &b, 2); return u;
}
__device__ __forceinline__ float bf2f(unsigned short h) {
    return __uint_as_float(((unsigned)h) << 16);
}
__device__ __forceinline__ unsigned pk2bf(float lo, float hi) {
    __hip_bfloat162 b2 = __float22bfloat162_rn(float2{lo, hi});
    unsigned u; __builtin_memcpy(&u, &b2, 4); return u;
}

// R12 (best measured: 11.91 us). ONE kernel, 256 blocks x 512 threads
// (1 block/CU). Block = 16 rows x all 512 cols. All contractions on MFMA:
// f = alpha@K (K-frags JIT in registers via multiplicative Gaussian
// recurrence, waves 0-1), Z = dw@ones (per-wave), out = dw@phi. phi(B)
// computed into LDS up front (multiplicative recurrence, restart /16),
// overlapping theta's HBM latency. 3 barriers.
__global__ __launch_bounds__(BT) void fused_kernel(
    const float* __restrict__ theta,
    const float* __restrict__ mu,
    const float* __restrict__ sigma,
    float* __restrict__ out, int Bn)
{
    __shared__ __align__(16) unsigned short sB[NB * AP];     // 139264 B
    __shared__ __align__(16) unsigned short sAlH[G * AP];    // alpha hi
    __shared__ __align__(16) unsigned short sAlL[G * AP];    // alpha lo
    __shared__ __align__(16) unsigned short sAh[G * AP];     // dw hi
    __shared__ __align__(16) unsigned short sAl[G * AP];     // dw lo
    __shared__ float s_f[G * 32];                            // f, t-42 in [0,32)
    __shared__ __align__(16) float s_muc[G];
    __shared__ __align__(16) float s_negth1[G];              // ~158.8 KB total

    const int tid  = threadIdx.x;
    const int b0   = blockIdx.x * G;
    const int lane = tid & 63;
    const int wv   = tid >> 6;
    const int lrow = lane & 15;
    const int kg   = (lane >> 4) * 8;

    // ---- issue all global loads up front ----
    const float mun = mu[tid];
    const float sgn = sigma[tid];
    float tv[5];
    #pragma unroll
    for (int k = 0; k < 5; ++k) {
        int i = tid + k * BT;
        int r = i / TC, c = i - r * TC;
        int br = b0 + r; if (br >= Bn) br = Bn - 1;
        tv[k] = (i < G * TC) ? theta[br * TC + c] : 0.0f;
    }

    // ---- Phase 0: B = phi bf16 [col][k]; multiplicative recurrence, restart /16 ----
    {
        const float inv_s = 1.0f / sgn;
        const float dlt = Hf * inv_s;
        const float Lh  = 0.5f * LOG2E;
        const float cc  = -2.0f * Lh * dlt * dlt;
        const float srt = __builtin_amdgcn_exp2f(cc);        // ratio-of-ratios
        const float S   = __log2f(0.3989422804014327f * inv_s);
        unsigned short* myB = &sB[tid * AP];
        #pragma unroll
        for (int k0 = 0; k0 < 96; k0 += 16) {
            float u  = (mun - Tval(k0)) * inv_s;
            float p  = __builtin_amdgcn_exp2f(S - Lh * u * u);
            float r  = __builtin_amdgcn_exp2f(Lh * dlt * (2.0f * u - dlt));
            unsigned w[8];
            #pragma unroll
            for (int j = 0; j < 8; ++j) {
                float p0 = p; p *= r; r *= srt;
                float p1 = p; p *= r; r *= srt;
                w[j] = pk2bf(p0, p1);
            }
            *(uint4*)&myB[k0]     = make_uint4(w[0], w[1], w[2], w[3]);
            *(uint4*)&myB[k0 + 8] = make_uint4(w[4], w[5], w[6], w[7]);
        }
        {   // k = 96..99 real, 100..127 zero pad
            float u  = (mun - Tval(96)) * inv_s;
            float p  = __builtin_amdgcn_exp2f(S - Lh * u * u);
            float r  = __builtin_amdgcn_exp2f(Lh * dlt * (2.0f * u - dlt));
            float p0 = p; p *= r; r *= srt;
            float p1 = p; p *= r; r *= srt;
            unsigned w0 = pk2bf(p0, p1);
            p0 = p; p *= r;
            p1 = p;
            unsigned w1 = pk2bf(p0, p1);
            *(uint4*)&myB[96]  = make_uint4(w0, w1, 0u, 0u);
            *(uint4*)&myB[104] = make_uint4(0u, 0u, 0u, 0u);
            *(uint4*)&myB[112] = make_uint4(0u, 0u, 0u, 0u);
            *(uint4*)&myB[120] = make_uint4(0u, 0u, 0u, 0u);
        }
    }

    // ---- Phase 1: theta -> alpha bf16 hi/lo + raw th0/th1 ----
    #pragma unroll
    for (int k = 0; k < 5; ++k) {
        int i = tid + k * BT;
        if (i < G * TC) {
            int r = i / TC, c = i - r * TC;
            float v = tv[k];
            if (c >= 2) {
                unsigned short h = f2bf(v);
                sAlH[r * AP + (c - 2)] = h;
                sAlL[r * AP + (c - 2)] = f2bf(v - bf2f(h));
            } else if (c == 0) s_muc[r] = v;
            else               s_negth1[r] = v;
        }
    }
    __syncthreads();   // B1

    // ---- Phase 2a: per-row scalars (lanes 0..15 of wave 0) ----
    if (tid < G) {
        float th1 = s_negth1[tid];            // <= -0.5
        s_muc[tid]    = s_muc[tid] * (-0.5f / th1);
        s_negth1[tid] = -th1;
    }

    // ---- Phase 2b: f = alpha @ K via MFMA; waves 0,1; K-frags via mult. recurrence ----
    if (wv < 2) {
        const int tcol = WLO + wv * 16 + lrow;
        const float T  = Tval(tcol);
        const float C2 = 50.0f * LOG2E;
        const float dj = 1.0f / 127.0f;
        const float sK = __builtin_amdgcn_exp2f(-2.0f * C2 * dj * dj);
        f32x4 fa = {0.0f, 0.0f, 0.0f, 0.0f};
        #pragma unroll
        for (int ks = 0; ks < 4; ++ks) {
            short8 ah = *(const short8*)&sAlH[lrow * AP + ks * 32 + kg];
            short8 al = *(const short8*)&sAlL[lrow * AP + ks * 32 + kg];
            float d0 = (float)(ks * 32 + kg) * dj - T;
            float p  = __builtin_amdgcn_exp2f(-C2 * d0 * d0);
            float r  = __builtin_amdgcn_exp2f(-C2 * dj * (2.0f * d0 + dj));
            short8 kh, kl;
            #pragma unroll
            for (int jj = 0; jj < 8; ++jj) {
                float kv = p; p *= r; r *= sK;
                unsigned short h = f2bf(kv);
                kh[jj] = (short)h;
                kl[jj] = (short)f2bf(kv - bf2f(h));
            }
            fa = __builtin_amdgcn_mfma_f32_16x16x32_bf16(ah, kh, fa, 0, 0, 0);
            fa = __builtin_amdgcn_mfma_f32_16x16x32_bf16(al, kh, fa, 0, 0, 0);
            fa = __builtin_amdgcn_mfma_f32_16x16x32_bf16(ah, kl, fa, 0, 0, 0);
        }
        #pragma unroll
        for (int j = 0; j < 4; ++j)
            s_f[((lane >> 4) * 4 + j) * 32 + wv * 16 + lrow] = fa[j];
    }
    __syncthreads();   // B2

    // ---- Phase 3: dw -> A bf16 hi/lo. Wave wv, round rd owns row rd*8+wv;
    //      lane handles t = 2*lane, 2*lane+1 ----
    #pragma unroll
    for (int rd = 0; rd < 2; ++rd) {
        const int row = rd * 8 + wv;
        const float muc = s_muc[row], nth = s_negth1[row];
        const int t0 = 2 * lane;
        float dw0 = 0.0f, dw1 = 0.0f;
        if (t0 < DXN) {
            unsigned i0 = (unsigned)(t0 - WLO);
            float f0 = (i0 < 32u) ? s_f[row * 32 + i0] : 0.0f;
            float dm0 = muc - Tval(t0);
            float e0 = fmaxf(1.0f + f0 - nth * dm0 * dm0, 1e-8f);
            dw0 = e0 * ((t0 == 0) ? Hf * 0.5f : Hf);
            const int t1 = t0 + 1;
            unsigned i1 = (unsigned)(t1 - WLO);
            float f1 = (i1 < 32u) ? s_f[row * 32 + i1] : 0.0f;
            float dm1 = muc - Tval(t1);
            float e1 = fmaxf(1.0f + f1 - nth * dm1 * dm1, 1e-8f);
            dw1 = e1 * ((t1 == DXN - 1) ? Hf * 0.5f : Hf);
        }
        unsigned short h0 = f2bf(dw0), h1 = f2bf(dw1);
        unsigned short l0 = f2bf(dw0 - bf2f(h0)), l1 = f2bf(dw1 - bf2f(h1));
        ((unsigned*)sAh)[row * (AP / 2) + lane] = ((unsigned)h1 << 16) | h0;
        ((unsigned*)sAl)[row * (AP / 2) + lane] = ((unsigned)l1 << 16) | l0;
    }
    __syncthreads();   // B3 (last barrier)

    // ---- Phase 4: A-frags, per-wave Z via ones-MFMA, GEMM vs sB, epilogue ----
    short8 Ah[4], Al[4];
    #pragma unroll
    for (int ks = 0; ks < 4; ++ks) {
        Ah[ks] = *(const short8*)&sAh[lrow * AP + ks * 32 + kg];
        Al[ks] = *(const short8*)&sAl[lrow * AP + ks * 32 + kg];
    }

    // per-wave Z: az[j] == Z[(lane>>4)*4+j] (every 16-lane group identical)
    short8 ones;
    #pragma unroll
    for (int jj = 0; jj < 8; ++jj) ones[jj] = (short)0x3F80;   // bf16 1.0
    f32x4 az = {0.0f, 0.0f, 0.0f, 0.0f};
    #pragma unroll
    for (int ks = 0; ks < 4; ++ks) {
        az = __builtin_amdgcn_mfma_f32_16x16x32_bf16(Ah[ks], ones, az, 0, 0, 0);
        az = __builtin_amdgcn_mfma_f32_16x16x32_bf16(Al[ks], ones, az, 0, 0, 0);
    }
    float iz[4];
    #pragma unroll
    for (int j = 0; j < 4; ++j) iz[j] = __builtin_amdgcn_rcpf(az[j]);

    #pragma unroll
    for (int ct = 0; ct < 4; ++ct) {
        const int n = wv * 64 + ct * 16 + lrow;
        f32x4 a = {0.0f, 0.0f, 0.0f, 0.0f};
        #pragma unroll
        for (int ks = 0; ks < 4; ++ks) {
            short8 b = *(const short8*)&sB[n * AP + ks * 32 + kg];
            a = __builtin_amdgcn_mfma_f32_16x16x32_bf16(Ah[ks], b, a, 0, 0, 0);
            a = __builtin_amdgcn_mfma_f32_16x16x32_bf16(Al[ks], b, a, 0, 0, 0);
        }
        #pragma unroll
        for (int j = 0; j < 4; ++j) {
            int row = b0 + (lane >> 4) * 4 + j;
            if (row < Bn) out[row * NB + n] = a[j] * iz[j];
        }
    }
}

extern "C" void kernel_launch(void* const* d_in, const int* in_sizes, int n_in,
                              void* d_out, int out_size, void* d_ws, size_t ws_size,
                              hipStream_t stream) {
    const float* theta = (const float*)d_in[0];
    const float* mu    = (const float*)d_in[1];
    const float* sigma = (const float*)d_in[2];
    float* outp = (float*)d_out;

    int Bn = in_sizes[0] / TC;                  // 4096
    int grid = (Bn + G - 1) / G;                // 256 blocks -> 1 per CU
    fused_kernel<<<grid, BT, 0, stream>>>(theta, mu, sigma, outp, Bn);
}